// Round 8
// baseline (121.289 us; speedup 1.0000x reference)
//
#include <hip/hip_runtime.h>

// NetSEIR r14: drain-immune pipeline - one-burst X preload into LDS.
//  r13 post-mortem: pipeline_kernel = ~41us wall but VALUBusy 0.015% ->
//  only ~5 chunks (~640 steps) of real work (~4us); ~36us is memory stall.
//  Mechanism: the 268MB ws poison fill retires into L2 and its dirty-line
//  drain to HBM continues ~41us into our kernel; the serial scan's cold X
//  reads / d_ws ring round-trip ride on a saturated memory system. This is
//  why r7-r13's very different scan bodies all landed within 4%.
//  r14: touch global once, wide and parallel, then run out of LDS:
//   - prologue: 8 waves copy X[0..2048 steps) (128KB) into LDS xpre
//     (16 coalesced float4 rounds);
//   - producers read X from xpre for chunks < 16 (t_conv~640 -> always),
//     global-X fallback for cb >= 16 kept for full-input correctness;
//   - rates ring + (E,Ic) handoff in LDS (r10 structure): wave0/wave1
//     touch only LDS; in-loop global traffic = wave1's ~13KB out stores.
//  LDS: 128K xpre + 8K rbuf + 2K sb ~= 141KB < 160KB, 1 block/CU.

typedef float v2 __attribute__((ext_vector_type(2)));

#define T_STEPS 1000000
#define CHUNK   128
#define NCHUNK  ((T_STEPS + CHUNK - 1) / CHUNK)    // 7813 (last partial)
#define TAU     512.0f
#define XPRE_CHUNKS 16
#define XPRE_STEPS  (XPRE_CHUNKS * CHUNK)          // 2048 steps = 128 KB

struct ConvRec { float S, E, I, Ic, R; int t; };

// ---------------------------------------------------------------------------
// rates quad: (rz = 1-sig, ry = sig, rx = beta/N, rw = gam)
// Templated on the X-quad pointer so LDS and global instantiations keep
// their address spaces distinct.
template <typename P>
__device__ __forceinline__ float4 rate_from(
    P xv,
    const float* __restrict__ wb,  const float* __restrict__ wb1,
    const float* __restrict__ wg,  const float* __restrict__ wg1,
    const float* __restrict__ wsg, const float* __restrict__ wsg1,
    float invN)
{
    float4 a = xv[0], b = xv[1], c = xv[2], d = xv[3];
    float x[16] = { a.x,a.y,a.z,a.w, b.x,b.y,b.z,b.w,
                    c.x,c.y,c.z,c.w, d.x,d.y,d.z,d.w };

    auto net = [&](const float* __restrict__ W, const float* __restrict__ w1) -> float {
        float z = 0.0f;
        #pragma unroll
        for (int j = 0; j < 8; ++j) {
            float h = 0.0f;
            #pragma unroll
            for (int i = 0; i < 16; ++i)
                h = fmaf(x[i], W[i * 8 + j], h);
            h = fmaxf(h, 0.0f);
            z = fmaf(h, w1[j], z);
        }
        return 1.0f / (1.0f + __expf(-z));
    };

    float beta = net(wb,  wb1);
    float sig  = net(wsg, wsg1);
    float gam  = net(wg,  wg1);
    return make_float4(1.0f - sig, sig, beta * invN, gam);
}

// one SEIR step, 5 VALU. q = (rz, ry, rx, rw).
#define STEP_PK(q)                                       \
    do {                                                 \
        float4 qq = (q);                                 \
        float P  = S * Ic;                               \
        v2 MW = (v2){qq.x, qq.y} * E;                    \
        v2 SE = (v2){-qq.z, qq.z} * P + (v2){S, MW.x};   \
        float T1 = fmaf(qq.y, E, W);                     \
        float Cn = fmaf(-qq.w, Ic, T1);                  \
        S = SE.x; E = SE.y; W = MW.y; Ic = Cn;           \
    } while (0)

// ---------------------------------------------------------------------------
// LDS safety (one __syncthreads per iter cb) - r10 invariants:
//  rbuf slot (cb+2)&3: written pre-bar(cb) by pair ((cb+2)%3); readers of
//    that slot (wave0/wave1 at iter cb+2) are >=1 barrier away on both
//    sides (lookahead 2, ring 4).
//  sb/sS/status[cb&1]: written pre-bar(cb), read post-bar(cb), overwritten
//    pre-bar(cb+2) with bar(cb+1) between.
//  xpre: written in prologue, read-only afterwards (one barrier after).
// All waves read status[cb&1] post-barrier -> identical break decision.
__global__ __launch_bounds__(512, 1) void pipeline_kernel(
    const float* __restrict__ X,
    const float* __restrict__ wb,  const float* __restrict__ wb1,
    const float* __restrict__ wg,  const float* __restrict__ wg1,
    const float* __restrict__ wsg, const float* __restrict__ wsg1,
    const float* __restrict__ Np,
    const float* __restrict__ init,
    float* __restrict__ out,
    ConvRec* __restrict__ conv)
{
    __shared__ __align__(16) float4 xpre[XPRE_STEPS * 4];  // 128 KB
    __shared__ __align__(16) float4 rbuf[4][CHUNK];        // rates ring (8 KB)
    __shared__ __align__(16) float2 sb[2][CHUNK];          // (E,Ic) handoff
    __shared__ float sS[2];
    __shared__ int   status[2];

    const int tid = threadIdx.x;
    const int wid = tid >> 6;
    const int l   = tid & 63;

    float* __restrict__ oS = out;
    float* __restrict__ oE = out + T_STEPS;
    float* __restrict__ oI = out + 2 * T_STEPS;
    float* __restrict__ oC = out + 3 * T_STEPS;
    float* __restrict__ oR = out + 4 * T_STEPS;

    // ---- prologue 1: one-burst X preload (the only bulk global read) ----
    {
        const float4* __restrict__ Xg = (const float4*)X;
        #pragma unroll
        for (int i = tid; i < XPRE_STEPS * 4; i += 512)
            xpre[i] = Xg[i];
    }

    // wave0 serial state (S,E,W=Iv,Ic) / wave1 carries
    float S = init[0], E = init[1], W = init[2], Ic = init[3];
    float Rbase = init[4], Ecarry = init[1], Ccarry = init[3];

    if (tid == 64) {                       // column 0 = init state
        oS[0] = S; oE[0] = E; oI[0] = W; oC[0] = Ic; oR[0] = Rbase;
    }

    const float invN = 1.0f / Np[0];
    auto produce = [&](int c, int half) {
        int t = c * CHUNK + half * 64 + l;
        float4 r;
        if (t >= T_STEPS)
            r = make_float4(1.0f, 0.0f, 0.0f, 0.0f);        // dummy (unused)
        else if (c < XPRE_CHUNKS)
            r = rate_from(&xpre[(size_t)t * 4],
                          wb, wb1, wg, wg1, wsg, wsg1, invN);
        else
            r = rate_from((const float4*)X + (size_t)t * 4,
                          wb, wb1, wg, wg1, wsg, wsg1, invN);
        rbuf[c & 3][half * 64 + l] = r;
    };

    __syncthreads();                       // xpre ready

    if (wid >= 2) {                        // prologue 2: chunks 0 and 1
        int pr = (wid - 2) >> 1, half = (wid - 2) & 1;
        if (pr < 2) produce(pr, half);
    }
    __syncthreads();

    int stopflag = 0;
    for (int cb = 0; cb < NCHUNK; ++cb) {
        const int bufp = cb & 1;
        const int col0 = cb * CHUNK + 1;

        if (wid == 0 && l == 0) {
            sS[bufp] = S;
            const float4* __restrict__ ratp = &rbuf[cb & 3][0];
            float4* __restrict__ pQ4 = (float4*)&sb[bufp][0];
            #pragma unroll 8
            for (int j = 0; j < CHUNK; j += 2) {
                STEP_PK(ratp[j]);
                float eA = E, cA = Ic;
                STEP_PK(ratp[j + 1]);
                pQ4[j >> 1] = make_float4(eA, cA, E, Ic);
            }
            bool cvg = (fabsf(E) < TAU) && (fabsf(W) < TAU) && (fabsf(Ic) < TAU);
            int sf = cvg ? 2 : ((cb == NCHUNK - 1) ? 1 : 0);
            status[bufp] = sf;
            if (sf) {
                conv->S = S; conv->E = E; conv->I = W; conv->Ic = Ic;
                conv->t = (sf == 2) ? ((cb + 1) * CHUNK + 1) : T_STEPS;
            }
        }
        if (wid >= 2) {                    // pair (pc%3) produces chunk cb+2
            int pc = cb + 2;
            int pr = (wid - 2) >> 1, half = (wid - 2) & 1;
            if (pc < NCHUNK && (pc % 3) == pr) produce(pc, half);
        }
        __syncthreads();
        stopflag = status[bufp];

        if (wid == 1) {
            float Sstart = sS[bufp];
            #pragma unroll
            for (int h = 0; h < 2; ++h) {
                int idx = h * 64 + l;
                float2 ec = sb[bufp][idx];
                float Ev = ec.x, Cv = ec.y;
                float Epre = __shfl_up(Ev, 1);
                float Cpre = __shfl_up(Cv, 1);
                if (l == 0) { Epre = Ecarry; Cpre = Ccarry; }

                float4 rme = rbuf[cb & 3][idx];   // (rz, ry, rx, rw)

                // S_col = S_start * prod_{k<=idx} (1 - rx_k * Ic_pre_k)
                float p = fmaf(-rme.z, Cpre, 1.0f);
                #pragma unroll
                for (int off = 1; off < 64; off <<= 1) {
                    float tv = __shfl_up(p, off);
                    if (l >= off) p *= tv;
                }
                float Scol = Sstart * p;

                // R_col = R_base + sum_{k<=idx} gam_k * Ic_pre_k
                float v = rme.w * Cpre;
                #pragma unroll
                for (int off = 1; off < 64; off <<= 1) {
                    float tv = __shfl_up(v, off);
                    if (l >= off) v += tv;
                }
                float Rcol = Rbase + v;

                Sstart *= __shfl(p, 63);
                Rbase  += __shfl(v, 63);
                Ecarry  = __shfl(Ev, 63);
                Ccarry  = __shfl(Cv, 63);

                int col = col0 + idx;
                if (col < T_STEPS) {
                    oS[col] = Scol; oE[col] = Ev; oC[col] = Cv;
                    oR[col] = Rcol; oI[col] = rme.y * Epre;
                }
            }
        }
        if (stopflag) break;
    }
    if (tid == 64) conv->R = Rbase;
}

// ---------------------------------------------------------------------------
// freeze pass, float4 quads: col quad fully >= t_conv -> 5 float4 stores;
// mixed/tail quad -> scalar. T_STEPS % 4 == 0 -> all rows 16B-aligned.
__global__ __launch_bounds__(256) void fill_kernel(
    const ConvRec* __restrict__ conv,
    float* __restrict__ out)
{
    int col = (blockIdx.x * 256 + threadIdx.x) * 4;
    if (col >= T_STEPS) return;
    ConvRec c = *conv;
    if (col + 4 <= T_STEPS && col >= c.t) {
        float4 vS = make_float4(c.S,  c.S,  c.S,  c.S);
        float4 vE = make_float4(c.E,  c.E,  c.E,  c.E);
        float4 vI = make_float4(c.I,  c.I,  c.I,  c.I);
        float4 vC = make_float4(c.Ic, c.Ic, c.Ic, c.Ic);
        float4 vR = make_float4(c.R,  c.R,  c.R,  c.R);
        *(float4*)(out + col)               = vS;
        *(float4*)(out + T_STEPS + col)     = vE;
        *(float4*)(out + 2 * T_STEPS + col) = vI;
        *(float4*)(out + 3 * T_STEPS + col) = vC;
        *(float4*)(out + 4 * T_STEPS + col) = vR;
    } else {
        #pragma unroll
        for (int k = 0; k < 4; ++k) {
            int cc = col + k;
            if (cc < T_STEPS && cc >= c.t) {
                out[cc]               = c.S;
                out[T_STEPS + cc]     = c.E;
                out[2 * T_STEPS + cc] = c.I;
                out[3 * T_STEPS + cc] = c.Ic;
                out[4 * T_STEPS + cc] = c.R;
            }
        }
    }
}

// ---------------------------------------------------------------------------
extern "C" void kernel_launch(void* const* d_in, const int* in_sizes, int n_in,
                              void* d_out, int out_size, void* d_ws, size_t ws_size,
                              hipStream_t stream)
{
    const float* X    = (const float*)d_in[0];
    const float* wb   = (const float*)d_in[1];
    const float* wb1  = (const float*)d_in[2];
    const float* wg   = (const float*)d_in[3];
    const float* wg1  = (const float*)d_in[4];
    const float* wsg  = (const float*)d_in[5];
    const float* wsg1 = (const float*)d_in[6];
    const float* init = (const float*)d_in[7];
    const float* Np   = (const float*)d_in[8];

    ConvRec* conv = (ConvRec*)d_ws;
    float*   out  = (float*)d_out;

    pipeline_kernel<<<1, 512, 0, stream>>>(
        X, wb, wb1, wg, wg1, wsg, wsg1, Np, init, out, conv);
    fill_kernel<<<(T_STEPS / 4 + 255) / 256, 256, 0, stream>>>(conv, out);
}

// Round 9
// 114.837 us; speedup vs baseline: 1.0562x; 1.0562x over previous
//
#include <hip/hip_runtime.h>

// NetSEIR r15 = r13 revert (measured best, 112.7us).
//  r14 post-mortem (+8.6us, real): the 128KB LDS X-preload serialized 16
//  per-thread load->ds_write round-trips (~900cy each) on the critical
//  path, replacing producer misses that were OVERLAPPED with compute.
//  Trace insight (r13): pipeline_kernel co-runs with the 268MB ws poison
//  fill on a parallel graph queue - its ~41us wall is the poison fill's
//  shadow, not its instruction stream. Controllable budget is only the
//  pipeline tail (~3us) + fill_kernel (~3.5us, at its 20MB write roofline)
//  + launch gaps; fusion to reclaim them measured +1.7us (r11, ~noise).
//  Structure (r13): producers -> global rates ring in d_ws (L1/L2-hot),
//  wave0 16-deep register double-buffer (static idx), LDS b128 (E,Ic)
//  handoff per 2 steps, wave1 S-product/R-sum scans + I row, float4 fill.

typedef float v2 __attribute__((ext_vector_type(2)));

#define T_STEPS 1000000
#define CHUNK   128
#define NCHUNK  ((T_STEPS + CHUNK - 1) / CHUNK)    // 7813 (last partial)
#define TAU     512.0f

struct ConvRec { float S, E, I, Ic, R; int t; };
// ws layout: ConvRec at +0; rates ring (4 slots x 128 x float4) at +1024.

// ---------------------------------------------------------------------------
// rates quad: (rz = 1-sig, ry = sig, rx = beta/N, rw = gam)
__device__ __forceinline__ float4 compute_rate(
    const float* __restrict__ X, int t,
    const float* __restrict__ wb,  const float* __restrict__ wb1,
    const float* __restrict__ wg,  const float* __restrict__ wg1,
    const float* __restrict__ wsg, const float* __restrict__ wsg1,
    float invN)
{
    const float4* xv = (const float4*)(X + (size_t)t * 16);
    float4 a = xv[0], b = xv[1], c = xv[2], d = xv[3];
    float x[16] = { a.x,a.y,a.z,a.w, b.x,b.y,b.z,b.w,
                    c.x,c.y,c.z,c.w, d.x,d.y,d.z,d.w };

    auto net = [&](const float* __restrict__ W, const float* __restrict__ w1) -> float {
        float z = 0.0f;
        #pragma unroll
        for (int j = 0; j < 8; ++j) {
            float h = 0.0f;
            #pragma unroll
            for (int i = 0; i < 16; ++i)
                h = fmaf(x[i], W[i * 8 + j], h);
            h = fmaxf(h, 0.0f);
            z = fmaf(h, w1[j], z);
        }
        return 1.0f / (1.0f + __expf(-z));
    };

    float beta = net(wb,  wb1);
    float sig  = net(wsg, wsg1);
    float gam  = net(wg,  wg1);
    return make_float4(1.0f - sig, sig, beta * invN, gam);
}

// one SEIR step, 5 VALU. q = (rz, ry, rx, rw).
#define STEP_PK(q)                                       \
    do {                                                 \
        float4 qq = (q);                                 \
        float P  = S * Ic;                               \
        v2 MW = (v2){qq.x, qq.y} * E;                    \
        v2 SE = (v2){-qq.z, qq.z} * P + (v2){S, MW.x};   \
        float T1 = fmaf(qq.y, E, W);                     \
        float Cn = fmaf(-qq.w, Ic, T1);                  \
        S = SE.x; E = SE.y; W = MW.y; Ic = Cn;           \
    } while (0)

// group g of 16 steps: prefetch the NEXT 16 rates into buf[(g+1)&1]
// (group 7 prefetches the next chunk's slot), consume buf[g&1], write
// (E,Ic) pairs to LDS as one b128 per 2 steps. g is a literal -> all
// buf indices compile-time-static (rule #20).
#define GROUP(g)                                                        \
    do {                                                                \
        const float4* __restrict__ src =                                \
            ((g) == 7) ? grn : (gr + ((g) + 1) * 16);                   \
        _Pragma("unroll")                                               \
        for (int j = 0; j < 16; ++j) buf[((g) + 1) & 1][j] = src[j];    \
        _Pragma("unroll")                                               \
        for (int j = 0; j < 16; j += 2) {                               \
            STEP_PK(buf[(g) & 1][j]);                                   \
            float eA = E, cA = Ic;                                      \
            STEP_PK(buf[(g) & 1][j + 1]);                               \
            pQ4[((g) * 16 + j) >> 1] = make_float4(eA, cA, E, Ic);      \
        }                                                               \
    } while (0)

// ---------------------------------------------------------------------------
// Safety (one __syncthreads per iter cb):
//  global ring slot (cb+2)&3: producers store pre-bar(cb); __syncthreads
//    drains their vmcnt -> visible. Readers: wave0 prefetch of slot
//    (cb+1)&3 during iter cb (written iter cb-1, bar(cb-1) between) and
//    slot cb&3 (written iter cb-2, 2 bars); wave1 reads slot cb&3
//    post-bar(cb). Slot rewrite at iter cb+2 is >=1 bar after last read.
//  sb/sS/status[cb&1] (LDS): written pre-bar(cb), read post-bar(cb),
//    overwritten pre-bar(cb+2) with bar(cb+1) between.
// All waves read status[cb&1] post-barrier -> identical break decision.
__global__ __launch_bounds__(512, 1) void pipeline_kernel(
    const float* __restrict__ X,
    const float* __restrict__ wb,  const float* __restrict__ wb1,
    const float* __restrict__ wg,  const float* __restrict__ wg1,
    const float* __restrict__ wsg, const float* __restrict__ wsg1,
    const float* __restrict__ Np,
    const float* __restrict__ init,
    float* __restrict__ out,
    ConvRec* __restrict__ conv,
    float4* __restrict__ ring)                       // 4*CHUNK float4 in d_ws
{
    __shared__ __align__(16) float2 sb[2][CHUNK];    // (E,Ic) handoff (2 KB)
    __shared__ float sS[2];
    __shared__ int   status[2];

    const int tid = threadIdx.x;
    const int wid = tid >> 6;
    const int l   = tid & 63;

    float* __restrict__ oS = out;
    float* __restrict__ oE = out + T_STEPS;
    float* __restrict__ oI = out + 2 * T_STEPS;
    float* __restrict__ oC = out + 3 * T_STEPS;
    float* __restrict__ oR = out + 4 * T_STEPS;

    // wave0 serial state (S,E,W=Iv,Ic) / wave1 carries
    float S = init[0], E = init[1], W = init[2], Ic = init[3];
    float Rbase = init[4], Ecarry = init[1], Ccarry = init[3];

    if (tid == 64) {                       // column 0 = init state
        oS[0] = S; oE[0] = E; oI[0] = W; oC[0] = Ic; oR[0] = Rbase;
    }

    const float invN = 1.0f / Np[0];
    auto produce = [&](int c, int half) {
        int t = c * CHUNK + half * 64 + l;
        float4 r = (t < T_STEPS)
            ? compute_rate(X, t, wb, wb1, wg, wg1, wsg, wsg1, invN)
            : make_float4(1.0f, 0.0f, 0.0f, 0.0f);   // dummy (never stored)
        ring[(c & 3) * CHUNK + half * 64 + l] = r;
    };

    if (wid >= 2) {                        // prologue: chunks 0 and 1
        int pr = (wid - 2) >> 1, half = (wid - 2) & 1;
        if (pr < 2) produce(pr, half);
    }
    __syncthreads();                       // drains producer vmcnt

    float4 buf[2][16];                     // wave0 rates double-buffer (VGPRs)
    if (tid == 0) {
        #pragma unroll
        for (int j = 0; j < 16; ++j) buf[0][j] = ring[j];   // chunk 0, group 0
    }

    int stopflag = 0;
    for (int cb = 0; cb < NCHUNK; ++cb) {
        const int bufp = cb & 1;
        const int col0 = cb * CHUNK + 1;

        if (wid == 0 && l == 0) {
            sS[bufp] = S;
            const float4* __restrict__ gr  = ring + (cb & 3) * CHUNK;
            const float4* __restrict__ grn = ring + ((cb + 1) & 3) * CHUNK;
            float4* __restrict__ pQ4 = (float4*)&sb[bufp][0];
            GROUP(0); GROUP(1); GROUP(2); GROUP(3);
            GROUP(4); GROUP(5); GROUP(6); GROUP(7);
            bool cvg = (fabsf(E) < TAU) && (fabsf(W) < TAU) && (fabsf(Ic) < TAU);
            int sf = cvg ? 2 : ((cb == NCHUNK - 1) ? 1 : 0);
            status[bufp] = sf;
            if (sf) {
                conv->S = S; conv->E = E; conv->I = W; conv->Ic = Ic;
                conv->t = (sf == 2) ? ((cb + 1) * CHUNK + 1) : T_STEPS;
            }
        }
        if (wid >= 2) {                    // pair (pc%3) produces chunk cb+2
            int pc = cb + 2;
            int pr = (wid - 2) >> 1, half = (wid - 2) & 1;
            if (pc < NCHUNK && (pc % 3) == pr) produce(pc, half);
        }
        __syncthreads();
        stopflag = status[bufp];

        if (wid == 1) {
            float Sstart = sS[bufp];
            #pragma unroll
            for (int h = 0; h < 2; ++h) {
                int idx = h * 64 + l;
                float2 ec = sb[bufp][idx];
                float Ev = ec.x, Cv = ec.y;
                float Epre = __shfl_up(Ev, 1);
                float Cpre = __shfl_up(Cv, 1);
                if (l == 0) { Epre = Ecarry; Cpre = Ccarry; }

                float4 rme = ring[(cb & 3) * CHUNK + idx];   // (rz,ry,rx,rw)

                // S_col = S_start * prod_{k<=idx} (1 - rx_k * Ic_pre_k)
                float p = fmaf(-rme.z, Cpre, 1.0f);
                #pragma unroll
                for (int off = 1; off < 64; off <<= 1) {
                    float tv = __shfl_up(p, off);
                    if (l >= off) p *= tv;
                }
                float Scol = Sstart * p;

                // R_col = R_base + sum_{k<=idx} gam_k * Ic_pre_k
                float v = rme.w * Cpre;
                #pragma unroll
                for (int off = 1; off < 64; off <<= 1) {
                    float tv = __shfl_up(v, off);
                    if (l >= off) v += tv;
                }
                float Rcol = Rbase + v;

                Sstart *= __shfl(p, 63);
                Rbase  += __shfl(v, 63);
                Ecarry  = __shfl(Ev, 63);
                Ccarry  = __shfl(Cv, 63);

                int col = col0 + idx;
                if (col < T_STEPS) {
                    oS[col] = Scol; oE[col] = Ev; oC[col] = Cv;
                    oR[col] = Rcol; oI[col] = rme.y * Epre;
                }
            }
        }
        if (stopflag) break;
    }
    if (tid == 64) conv->R = Rbase;
}

// ---------------------------------------------------------------------------
// freeze pass, float4 quads: col quad fully >= t_conv -> 5 float4 stores;
// mixed/tail quad -> scalar. T_STEPS % 4 == 0 -> all rows 16B-aligned.
__global__ __launch_bounds__(256) void fill_kernel(
    const ConvRec* __restrict__ conv,
    float* __restrict__ out)
{
    int col = (blockIdx.x * 256 + threadIdx.x) * 4;
    if (col >= T_STEPS) return;
    ConvRec c = *conv;
    if (col + 4 <= T_STEPS && col >= c.t) {
        float4 vS = make_float4(c.S,  c.S,  c.S,  c.S);
        float4 vE = make_float4(c.E,  c.E,  c.E,  c.E);
        float4 vI = make_float4(c.I,  c.I,  c.I,  c.I);
        float4 vC = make_float4(c.Ic, c.Ic, c.Ic, c.Ic);
        float4 vR = make_float4(c.R,  c.R,  c.R,  c.R);
        *(float4*)(out + col)               = vS;
        *(float4*)(out + T_STEPS + col)     = vE;
        *(float4*)(out + 2 * T_STEPS + col) = vI;
        *(float4*)(out + 3 * T_STEPS + col) = vC;
        *(float4*)(out + 4 * T_STEPS + col) = vR;
    } else {
        #pragma unroll
        for (int k = 0; k < 4; ++k) {
            int cc = col + k;
            if (cc < T_STEPS && cc >= c.t) {
                out[cc]               = c.S;
                out[T_STEPS + cc]     = c.E;
                out[2 * T_STEPS + cc] = c.I;
                out[3 * T_STEPS + cc] = c.Ic;
                out[4 * T_STEPS + cc] = c.R;
            }
        }
    }
}

// ---------------------------------------------------------------------------
extern "C" void kernel_launch(void* const* d_in, const int* in_sizes, int n_in,
                              void* d_out, int out_size, void* d_ws, size_t ws_size,
                              hipStream_t stream)
{
    const float* X    = (const float*)d_in[0];
    const float* wb   = (const float*)d_in[1];
    const float* wb1  = (const float*)d_in[2];
    const float* wg   = (const float*)d_in[3];
    const float* wg1  = (const float*)d_in[4];
    const float* wsg  = (const float*)d_in[5];
    const float* wsg1 = (const float*)d_in[6];
    const float* init = (const float*)d_in[7];
    const float* Np   = (const float*)d_in[8];

    ConvRec* conv = (ConvRec*)d_ws;
    float4*  ring = (float4*)((char*)d_ws + 1024);
    float*   out  = (float*)d_out;

    pipeline_kernel<<<1, 512, 0, stream>>>(
        X, wb, wb1, wg, wg1, wsg, wsg1, Np, init, out, conv, ring);
    fill_kernel<<<(T_STEPS / 4 + 255) / 256, 256, 0, stream>>>(conv, out);
}